// Round 5
// baseline (97.994 us; speedup 1.0000x reference)
//
#include <hip/hip_runtime.h>
#include <math.h>

// Sparsemax along last dim, rows of d=2048, fp32.
// One wave per row; row in registers (32 floats/lane). tau via Michelot from
// the exact bound tau* >= -1 (shifted max=0, p_max <= 1).
// Residual form: r = sum(max(a - t, 0)) over the row; exact update
//   tau += (r - 1)/c,   c = |{a > t}|  (count via ballot -> SALU, no butterfly)
// Converged when c unchanged (nested sets). Output: max(a - (mx+tau), 0).

constexpr int D      = 2048;
constexpr int LANES  = 64;
constexpr int PER    = D / LANES;   // 32 elements per lane
constexpr int WAVES  = 4;           // waves (rows) per block
constexpr int BLOCK  = WAVES * LANES;

typedef float f32x4 __attribute__((ext_vector_type(4)));

__global__ __launch_bounds__(BLOCK, 8)   // 8 waves/EU
void sparsemax_kernel(const float* __restrict__ X, float* __restrict__ Y, int nrows)
{
    const int wid  = threadIdx.x >> 6;
    const int lane = threadIdx.x & 63;
    const int row  = blockIdx.x * WAVES + wid;
    if (row >= nrows) return;

    const f32x4* __restrict__ px = reinterpret_cast<const f32x4*>(X) + (size_t)row * (D / 4);
    f32x4*       __restrict__ py = reinterpret_cast<f32x4*>(Y)       + (size_t)row * (D / 4);

    // ---- load row (nontemporal, coalesced: lane reads float4 at [j*64+lane]) ----
    float a[PER];
    #pragma unroll
    for (int j = 0; j < PER / 4; ++j) {
        f32x4 v = __builtin_nontemporal_load(&px[j * LANES + lane]);
        a[4*j+0] = v.x; a[4*j+1] = v.y; a[4*j+2] = v.z; a[4*j+3] = v.w;
    }

    // ---- row max: tree reduce in-lane (depth 5), then 6-step butterfly ----
    float tmax[16];
    #pragma unroll
    for (int i = 0; i < 16; ++i) tmax[i] = fmaxf(a[2*i], a[2*i+1]);
    #pragma unroll
    for (int i = 0; i < 8; ++i)  tmax[i] = fmaxf(tmax[2*i], tmax[2*i+1]);
    #pragma unroll
    for (int i = 0; i < 4; ++i)  tmax[i] = fmaxf(tmax[2*i], tmax[2*i+1]);
    float mx = fmaxf(fmaxf(tmax[0], tmax[1]), fmaxf(tmax[2], tmax[3]));
    #pragma unroll
    for (int off = 32; off >= 1; off >>= 1)
        mx = fmaxf(mx, __shfl_xor(mx, off));

    // ---- Michelot, residual form ----
    float tau   = -1.0f;
    int   cprev = -1;

    for (int it = 0; it < D; ++it) {              // cap for guaranteed termination
        const float t = mx + tau;                 // unshifted threshold
        float racc[4] = {0.0f, 0.0f, 0.0f, 0.0f};
        int   cnt = 0;
        #pragma unroll
        for (int i = 0; i < PER; ++i) {
            float d = a[i] - t;
            racc[i & 3] += fmaxf(d, 0.0f);
            cnt += (int)__popcll(__ballot(d > 0.0f));   // SALU count, wave-uniform
        }
        float r = (racc[0] + racc[1]) + (racc[2] + racc[3]);
        #pragma unroll
        for (int off = 32; off >= 1; off >>= 1)
            r += __shfl_xor(r, off);

        tau += (r - 1.0f) * __builtin_amdgcn_rcpf((float)cnt);  // c >= 1 always
        if (cnt == cprev) break;                  // same count + nested -> exact
        cprev = cnt;
    }

    // ---- write output: max(a - T, 0), T = mx + tau (nontemporal) ----
    const float T = mx + tau;
    #pragma unroll
    for (int j = 0; j < PER / 4; ++j) {
        f32x4 v;
        v.x = fmaxf(a[4*j+0] - T, 0.0f);
        v.y = fmaxf(a[4*j+1] - T, 0.0f);
        v.z = fmaxf(a[4*j+2] - T, 0.0f);
        v.w = fmaxf(a[4*j+3] - T, 0.0f);
        __builtin_nontemporal_store(v, &py[j * LANES + lane]);
    }
}

extern "C" void kernel_launch(void* const* d_in, const int* in_sizes, int n_in,
                              void* d_out, int out_size, void* d_ws, size_t ws_size,
                              hipStream_t stream)
{
    const float* X = reinterpret_cast<const float*>(d_in[0]);
    float*       Y = reinterpret_cast<float*>(d_out);
    const int nrows = in_sizes[0] / D;                 // 32768
    const int grid  = (nrows + WAVES - 1) / WAVES;     // 8192 blocks
    sparsemax_kernel<<<grid, BLOCK, 0, stream>>>(X, Y, nrows);
}